// Round 17
// baseline (853.788 us; speedup 1.0000x reference)
//
#include <hip/hip_runtime.h>

// SimpleRNN: x(256,2048,8) f32, h(1,256,128), W_ih(128,8), W_hh(128,128),
// b_ih(128), b_hh(128), W_head(1,128), b_head(1)
// out = [pred(256) | last_step_features(256,128) | h_n(256,128)]  (f32)
//
// R15: R10 skeleton (verified), 2 waves x 4 outputs/lane -> DS insts/CU-step
// 36 -> 18 (the cross-round binder: DS pipe @ ~12cy/inst). ONLY verified
// primitives: quad_perm DPP reduce (R1..R12), PK_FMA op_sel (R4/R10..R12),
// LDS-sourced weights for true residency (R12: ds_read not remat'able),
// rotated conflict-free h reads (R10), ping-pong h + lgkm-only barrier (R10),
// f32x2 direct-global x pipeline (R10). No novel DPP ctrls (R13/R14 lesson).

typedef float f32x2 __attribute__((ext_vector_type(2)));
typedef float f32x4 __attribute__((ext_vector_type(4)));

#define BB 256
#define TT 2048
#define II 8
#define HH 128
#define THREADS 128

// v_pk_fma_f32, src0 LO/HI half broadcast to both halves (verified R4/R10)
#define PK_FMA_LO(acc, hp, wp) \
    asm("v_pk_fma_f32 %0, %1, %2, %0 op_sel:[0,0,0] op_sel_hi:[0,1,1]" \
        : "+v"(acc) : "v"(hp), "v"(wp))
#define PK_FMA_HI(acc, hp, wp) \
    asm("v_pk_fma_f32 %0, %1, %2, %0 op_sel:[1,0,0] op_sel_hi:[1,1,1]" \
        : "+v"(acc) : "v"(hp), "v"(wp))

__device__ __forceinline__ float quad_sum(float x) {
    // xor1 + xor2 butterfly within each aligned 4-lane quad (verified)
    int xi = __builtin_bit_cast(int, x);
    int y1 = __builtin_amdgcn_update_dpp(0, xi, 0xB1, 0xF, 0xF, true); // [1,0,3,2]
    float s1 = x + __builtin_bit_cast(float, y1);
    int s1i = __builtin_bit_cast(int, s1);
    int y2 = __builtin_amdgcn_update_dpp(0, s1i, 0x4E, 0xF, 0xF, true); // [2,3,0,1]
    return s1 + __builtin_bit_cast(float, y2);
}

__global__ void
__launch_bounds__(THREADS, 1)
__attribute__((amdgpu_waves_per_eu(1, 1)))
rnn_v15_kernel(const float* __restrict__ x,
               const float* __restrict__ h0,
               const float* __restrict__ W_ih,
               const float* __restrict__ W_hh,
               const float* __restrict__ b_ih,
               const float* __restrict__ b_hh,
               const float* __restrict__ W_head,
               const float* __restrict__ b_head,
               float* __restrict__ out)
{
    __shared__ __align__(16) float W_lds[HH * HH];   // full W_hh, 64 KB
    __shared__ __align__(16) float h_lds[2][HH];     // ping-pong hidden state
    __shared__ float part[HH];

    const int b    = blockIdx.x;
    const int tid  = threadIdx.x;
    const int w    = tid >> 6;        // wave 0..1
    const int lane = tid & 63;
    const int jg   = lane >> 2;       // 0..15
    const int kc   = lane & 3;        // 0..3 (32-float k-chunk)
    const int j0   = w * 64 + jg * 4; // this lane's 4 outputs j0..j0+3

    // ---- stage W_hh global -> LDS, coalesced ----
    {
        const f32x4* Wg = (const f32x4*)W_hh;
        f32x4*       Wl = (f32x4*)W_lds;
        #pragma unroll
        for (int q = 0; q < 32; ++q)
            Wl[q * THREADS + tid] = Wg[q * THREADS + tid];
    }
    h_lds[0][tid] = h0[b * HH + tid];
    __syncthreads();

    // ---- weights from LDS (non-remat'able => resident; R12 mechanism) ----
    // rotated READ order: slot i holds column block m=(i+2kc)&7 of this kc chunk
    // wjA[4i+c] = (W[j0][kc*32+4m+c], W[j0+1][..]), wjB same for j0+2/j0+3
    f32x2 wjA[32], wjB[32];
    {
        const float* r0 = W_lds + j0 * HH + kc * 32;
        const float* r1 = r0 + HH;
        const float* r2 = r0 + 2 * HH;
        const float* r3 = r0 + 3 * HH;
        #pragma unroll
        for (int i = 0; i < 8; ++i) {
            const int m = (i + 2 * kc) & 7;
            #pragma unroll
            for (int c = 0; c < 4; ++c) {
                wjA[4 * i + c] = (f32x2){r0[4 * m + c], r1[4 * m + c]};
                wjB[4 * i + c] = (f32x2){r2[4 * m + c], r3[4 * m + c]};
            }
        }
    }
    const f32x2 wx01_0 = (f32x2){W_ih[j0 * II + 2 * kc],       W_ih[(j0 + 1) * II + 2 * kc]};
    const f32x2 wx01_1 = (f32x2){W_ih[j0 * II + 2 * kc + 1],   W_ih[(j0 + 1) * II + 2 * kc + 1]};
    const f32x2 wx23_0 = (f32x2){W_ih[(j0 + 2) * II + 2 * kc], W_ih[(j0 + 3) * II + 2 * kc]};
    const f32x2 wx23_1 = (f32x2){W_ih[(j0 + 2) * II + 2 * kc + 1], W_ih[(j0 + 3) * II + 2 * kc + 1]};
    const f32x2 b01 = (f32x2){0.25f * (b_ih[j0] + b_hh[j0]),
                              0.25f * (b_ih[j0 + 1] + b_hh[j0 + 1])};
    const f32x2 b23 = (f32x2){0.25f * (b_ih[j0 + 2] + b_hh[j0 + 2]),
                              0.25f * (b_ih[j0 + 3] + b_hh[j0 + 3])};

    // x: direct global f32x2 loads, 2-step register pipeline (R10-verified)
    const float* xk = x + (size_t)b * TT * II + 2 * kc;
    f32x2 xe = *(const f32x2*)(xk + 0 * II);
    f32x2 xo = *(const f32x2*)(xk + 1 * II);

    #define STEP(XV, RBUF, TN)                                                   \
    {                                                                            \
        f32x2 a0 = b01, a1 = (f32x2){0.f, 0.f};                                  \
        f32x2 a2 = (f32x2){0.f, 0.f}, a3 = (f32x2){0.f, 0.f};                    \
        f32x2 c0 = b23, c1 = (f32x2){0.f, 0.f};                                  \
        f32x2 c2 = (f32x2){0.f, 0.f}, c3 = (f32x2){0.f, 0.f};                    \
        PK_FMA_LO(a0, XV, wx01_0);                                               \
        PK_FMA_HI(a1, XV, wx01_1);                                               \
        PK_FMA_LO(c0, XV, wx23_0);                                               \
        PK_FMA_HI(c1, XV, wx23_1);                                               \
        _Pragma("unroll")                                                        \
        for (int i = 0; i < 8; i += 2) {                                         \
            const f32x4 hva = *(const f32x4*)                                    \
                &h_lds[RBUF][kc * 32 + (((i + 0) + 2 * kc) & 7) * 4];            \
            const f32x4 hvb = *(const f32x4*)                                    \
                &h_lds[RBUF][kc * 32 + (((i + 1) + 2 * kc) & 7) * 4];            \
            const f32x2 ha01 = __builtin_shufflevector(hva, hva, 0, 1);          \
            const f32x2 ha23 = __builtin_shufflevector(hva, hva, 2, 3);          \
            const f32x2 hb01 = __builtin_shufflevector(hvb, hvb, 0, 1);          \
            const f32x2 hb23 = __builtin_shufflevector(hvb, hvb, 2, 3);          \
            PK_FMA_LO(a0, ha01, wjA[4 * i + 0]);                                 \
            PK_FMA_HI(a1, ha01, wjA[4 * i + 1]);                                 \
            PK_FMA_LO(a2, ha23, wjA[4 * i + 2]);                                 \
            PK_FMA_HI(a3, ha23, wjA[4 * i + 3]);                                 \
            PK_FMA_LO(c0, ha01, wjB[4 * i + 0]);                                 \
            PK_FMA_HI(c1, ha01, wjB[4 * i + 1]);                                 \
            PK_FMA_LO(c2, ha23, wjB[4 * i + 2]);                                 \
            PK_FMA_HI(c3, ha23, wjB[4 * i + 3]);                                 \
            PK_FMA_LO(a0, hb01, wjA[4 * i + 4]);                                 \
            PK_FMA_HI(a1, hb01, wjA[4 * i + 5]);                                 \
            PK_FMA_LO(a2, hb23, wjA[4 * i + 6]);                                 \
            PK_FMA_HI(a3, hb23, wjA[4 * i + 7]);                                 \
            PK_FMA_LO(c0, hb01, wjB[4 * i + 4]);                                 \
            PK_FMA_HI(c1, hb01, wjB[4 * i + 5]);                                 \
            PK_FMA_LO(c2, hb23, wjB[4 * i + 6]);                                 \
            PK_FMA_HI(c3, hb23, wjB[4 * i + 7]);                                 \
        }                                                                        \
        const f32x2 s01 = (a0 + a1) + (a2 + a3);                                 \
        const f32x2 s23 = (c0 + c1) + (c2 + c3);                                 \
        const float s0 = quad_sum(s01.x);                                        \
        const float s1 = quad_sum(s01.y);                                        \
        const float s2 = quad_sum(s23.x);                                        \
        const float s3 = quad_sum(s23.y);                                        \
        const float e0 = __builtin_amdgcn_exp2f(s0 * 2.8853900817779268f);       \
        const float e1 = __builtin_amdgcn_exp2f(s1 * 2.8853900817779268f);       \
        const float e2 = __builtin_amdgcn_exp2f(s2 * 2.8853900817779268f);       \
        const float e3 = __builtin_amdgcn_exp2f(s3 * 2.8853900817779268f);       \
        f32x4 th;                                                                \
        th.x = 1.0f - 2.0f * __builtin_amdgcn_rcpf(e0 + 1.0f);                   \
        th.y = 1.0f - 2.0f * __builtin_amdgcn_rcpf(e1 + 1.0f);                   \
        th.z = 1.0f - 2.0f * __builtin_amdgcn_rcpf(e2 + 1.0f);                   \
        th.w = 1.0f - 2.0f * __builtin_amdgcn_rcpf(e3 + 1.0f);                   \
        if (kc == 0) *(f32x4*)&h_lds[(RBUF) ^ 1][j0] = th;                       \
        { const int tn_ = (TN) < TT ? (TN) : (TT - 1);                           \
          XV = *(const f32x2*)(xk + (size_t)tn_ * II); }                         \
        asm volatile("s_waitcnt lgkmcnt(0)\n\ts_barrier" ::: "memory");          \
    }

    for (int t = 0; t < TT; t += 2) {
        STEP(xe, 0, t + 2)   // even step: reads buf0, writes buf1
        STEP(xo, 1, t + 3)   // odd  step: reads buf1, writes buf0
    }
    #undef STEP

    // ---- epilogue: final h in h_lds[0] (t=2047 odd wrote buf 0) ----
    {
        const float hl = h_lds[0][tid];
        out[BB + b * HH + tid]           = hl;   // last_step_features
        out[BB + BB * HH + b * HH + tid] = hl;   // h_n
        part[tid] = hl * W_head[tid];
    }
    __syncthreads();
    if (w == 0) {
        float s = part[lane] + part[lane + 64];
        #pragma unroll
        for (int off = 32; off > 0; off >>= 1) s += __shfl_down(s, off);
        if (lane == 0) out[b] = s + b_head[0];
    }
}

extern "C" void kernel_launch(void* const* d_in, const int* in_sizes, int n_in,
                              void* d_out, int out_size, void* d_ws, size_t ws_size,
                              hipStream_t stream) {
    const float* x      = (const float*)d_in[0];
    const float* h0     = (const float*)d_in[1];
    const float* W_ih   = (const float*)d_in[2];
    const float* W_hh   = (const float*)d_in[3];
    const float* b_ih   = (const float*)d_in[4];
    const float* b_hh   = (const float*)d_in[5];
    const float* W_head = (const float*)d_in[6];
    const float* b_head = (const float*)d_in[7];
    float* out = (float*)d_out;

    hipLaunchKernelGGL(rnn_v15_kernel, dim3(BB), dim3(THREADS), 0, stream,
                       x, h0, W_ih, W_hh, b_ih, b_hh, W_head, b_head, out);
}